// Round 14
// baseline (570.337 us; speedup 1.0000x reference)
//
#include <hip/hip_runtime.h>
#include <cstdint>
#include <cstddef>

#define NN 100000
#define NEDGE 800000
#define NBUCK 196          // node buckets: id = node >> 9 (512 nodes per bucket)
#define RNG 512
#define CAP 5120           // fixed bucket capacity: mean 4096, sigma ~64 -> 16-sigma headroom

typedef __attribute__((ext_vector_type(8))) short short8v;
typedef __attribute__((ext_vector_type(16))) float float16v;

__device__ inline ushort f2bf(float f) {
    uint32_t u = __float_as_uint(f);
    u += 0x7fff + ((u >> 16) & 1);   // round-to-nearest-even
    return (ushort)(u >> 16);
}
__device__ inline float bf2f(ushort h) { return __uint_as_float(((uint32_t)h) << 16); }

__device__ inline void gload16(const void* g, void* lds) {
    __builtin_amdgcn_global_load_lds(
        (const __attribute__((address_space(1))) void*)g,
        (__attribute__((address_space(3))) void*)lds, 16, 0, 0);
}

// ================= bucketed CSR build (fixed-capacity buckets) =================

__global__ void initCur(int* __restrict__ dstCur, int* __restrict__ srcCur) {
    int i = threadIdx.x;
    if (i < NBUCK) { dstCur[i] = i * CAP; srcCur[i] = i * CAP; }
}

__global__ __launch_bounds__(256) void partition_kernel(
        const int* __restrict__ src, const int* __restrict__ dst,
        int* __restrict__ dstCur, int* __restrict__ srcCur,
        int2* __restrict__ pairBuck, int* __restrict__ srcBuck, int E) {
    __shared__ int cd[NBUCK], bd[NBUCK], cs[NBUCK], bs[NBUCK];
    const int CH = (E + gridDim.x - 1) / gridDim.x;
    const int lo = blockIdx.x * CH;
    const int hi = min(lo + CH, E);
    for (int i = threadIdx.x; i < NBUCK; i += 256) { cd[i] = 0; cs[i] = 0; }
    __syncthreads();
    for (int i = lo + threadIdx.x; i < hi; i += 256) {
        atomicAdd(&cd[dst[i] >> 9], 1);
        atomicAdd(&cs[src[i] >> 9], 1);
    }
    __syncthreads();
    for (int i = threadIdx.x; i < NBUCK; i += 256) {
        bd[i] = cd[i] ? atomicAdd(&dstCur[i], cd[i]) : 0;
        bs[i] = cs[i] ? atomicAdd(&srcCur[i], cs[i]) : 0;
        cd[i] = 0; cs[i] = 0;
    }
    __syncthreads();
    for (int i = lo + threadIdx.x; i < hi; i += 256) {
        int s = src[i], d = dst[i];
        int slot = atomicAdd(&cd[d >> 9], 1);
        pairBuck[bd[d >> 9] + slot] = make_int2(s, d);
        int slot2 = atomicAdd(&cs[s >> 9], 1);
        srcBuck[bs[s >> 9] + slot2] = s;
    }
}

// per-bucket src histogram -> ns; fused conversion of this bucket's x rows to bf16*ns
__global__ __launch_bounds__(256) void srcHistConv(
        const int* __restrict__ srcBuck, const int* __restrict__ srcCur,
        const float* __restrict__ x, float* __restrict__ ns,
        ushort* __restrict__ actB, int n) {
    __shared__ int h[RNG];
    __shared__ float sns[RNG];
    const int k = blockIdx.x;
    for (int i = threadIdx.x; i < RNG; i += 256) h[i] = 0;
    __syncthreads();
    const int lo = k * CAP, hi = srcCur[k];
    for (int i = lo + threadIdx.x; i < hi; i += 256)
        atomicAdd(&h[srcBuck[i] & (RNG - 1)], 1);
    __syncthreads();
    for (int i = threadIdx.x; i < RNG; i += 256) {
        float v = 1.0f / sqrtf((float)max(h[i], 1));
        sns[i] = v;
        int idx = k * RNG + i;
        if (idx < n) ns[idx] = v;
    }
    __syncthreads();
    const int base = k * RNG;
    for (int i = threadIdx.x; i < RNG * 32; i += 256) {
        int nl = i >> 5;
        int node = base + nl;
        if (node < n) {
            int f0 = (i & 31) * 4;
            float sc = sns[nl];
            float4 v = *reinterpret_cast<const float4*>(x + (size_t)node * 128 + f0);
            ushort4 hh;
            hh.x = f2bf(v.x * sc);
            hh.y = f2bf(v.y * sc);
            hh.z = f2bf(v.z * sc);
            hh.w = f2bf(v.w * sc);
            *reinterpret_cast<ushort4*>(actB + (size_t)node * 128 + f0) = hh;
        }
    }
}

// per-bucket dst histogram + scan -> rowse (start,end), nd; LDS-cursor scatter
__global__ __launch_bounds__(256) void dstBuild(const int2* __restrict__ pairBuck,
                                                const int* __restrict__ dstCur,
                                                float* __restrict__ nd, int2* __restrict__ rowse,
                                                int* __restrict__ permSrc, int n) {
    __shared__ int h[RNG];
    __shared__ int tsum[256];
    const int k = blockIdx.x;
    const int t = threadIdx.x;
    for (int i = t; i < RNG; i += 256) h[i] = 0;
    __syncthreads();
    const int lo = k * CAP, hi = dstCur[k];
    for (int i = lo + t; i < hi; i += 256)
        atomicAdd(&h[pairBuck[i].y & (RNG - 1)], 1);
    __syncthreads();
    int a0 = h[2 * t], a1 = h[2 * t + 1];
    tsum[t] = a0 + a1;
    __syncthreads();
    for (int off = 1; off < 256; off <<= 1) {
        int v = (t >= off) ? tsum[t - off] : 0;
        __syncthreads();
        tsum[t] += v;
        __syncthreads();
    }
    const int pre = lo + (t > 0 ? tsum[t - 1] : 0);
    const int r0 = pre, r1 = pre + a0;
    const int idx0 = k * RNG + 2 * t;
    if (idx0 < n)     { rowse[idx0]     = make_int2(r0, r1);      nd[idx0]     = 1.0f / sqrtf((float)max(a0, 1)); }
    if (idx0 + 1 < n) { rowse[idx0 + 1] = make_int2(r1, r1 + a1); nd[idx0 + 1] = 1.0f / sqrtf((float)max(a1, 1)); }
    h[2 * t] = r0;
    h[2 * t + 1] = r1;
    __syncthreads();
    for (int i = lo + t; i < hi; i += 256) {
        int2 p = pairBuck[i];
        int pos = atomicAdd(&h[p.y & (RNG - 1)], 1);
        permSrc[pos] = p.x;
    }
}

// ================= converters =================

__global__ void convw_all(const float* __restrict__ W0, const float* __restrict__ W1,
                          const float* __restrict__ W2, const float* __restrict__ W3,
                          ushort* __restrict__ Wt) {
    int idx = blockIdx.x * blockDim.x + threadIdx.x;
    if (idx >= 131072) return;
    const float* W; int K, logD, base;
    if (idx < 16384)      { W = W0; K = 128; logD = 7; base = 0; }
    else if (idx < 32768) { W = W1; K = 128; logD = 7; base = 16384; }
    else if (idx < 65536) { W = W2; K = 128; logD = 8; base = 32768; }
    else                  { W = W3; K = 256; logD = 8; base = 65536; }
    int loc = idx - base;
    int k = loc >> logD, d = loc & ((1 << logD) - 1);
    Wt[base + d * K + k] = f2bf(W[loc]);
}

// ================= CSR aggregation: 16B gather loads, edge-group MLP =================
// Rb[node] = bf16( nd[node] * sum_{e in CSR(node)} act[src[e]] )

__device__ inline void accum8(float* a, uint4 v) {
    a[0] += __uint_as_float(v.x << 16);
    a[1] += __uint_as_float(v.x & 0xffff0000u);
    a[2] += __uint_as_float(v.y << 16);
    a[3] += __uint_as_float(v.y & 0xffff0000u);
    a[4] += __uint_as_float(v.z << 16);
    a[5] += __uint_as_float(v.z & 0xffff0000u);
    a[6] += __uint_as_float(v.w << 16);
    a[7] += __uint_as_float(v.w & 0xffff0000u);
}

template<int D>
__global__ __launch_bounds__(256) void agg_kernel(
        const ushort* __restrict__ act, const int2* __restrict__ rowse,
        const int* __restrict__ permSrc, const float* __restrict__ nd,
        ushort* __restrict__ Rb, int n) {
    int node = blockIdx.x * 4 + (threadIdx.x >> 6);
    if (node >= n) return;
    int lane = threadIdx.x & 63;
    constexpr int GROUPS = (D == 256) ? 2 : 4;   // edge slices per wave
    constexpr int GL = 64 / GROUPS;              // lanes per slice (32 / 16)
    const int g  = lane / GL;
    const int gl = lane % GL;
    const int f0 = gl * 8;                       // 8 bf16 per lane (16B)
    float a[8] = {0.f,0.f,0.f,0.f,0.f,0.f,0.f,0.f};
    int2 se = rowse[node];
    int r0 = se.x, r1 = se.y;

    int e = r0 + g;
    for (; e + 3 * GROUPS < r1; e += 4 * GROUPS) {
        int s0 = permSrc[e];
        int s1 = permSrc[e + GROUPS];
        int s2 = permSrc[e + 2 * GROUPS];
        int s3 = permSrc[e + 3 * GROUPS];
        uint4 v0 = *reinterpret_cast<const uint4*>(act + (size_t)s0 * D + f0);
        uint4 v1 = *reinterpret_cast<const uint4*>(act + (size_t)s1 * D + f0);
        uint4 v2 = *reinterpret_cast<const uint4*>(act + (size_t)s2 * D + f0);
        uint4 v3 = *reinterpret_cast<const uint4*>(act + (size_t)s3 * D + f0);
        accum8(a, v0); accum8(a, v1); accum8(a, v2); accum8(a, v3);
    }
    // 2x unrolled middle: keeps 2 gathers in flight at low remaining degree
    for (; e + GROUPS < r1; e += 2 * GROUPS) {
        int s0 = permSrc[e];
        int s1 = permSrc[e + GROUPS];
        uint4 v0 = *reinterpret_cast<const uint4*>(act + (size_t)s0 * D + f0);
        uint4 v1 = *reinterpret_cast<const uint4*>(act + (size_t)s1 * D + f0);
        accum8(a, v0); accum8(a, v1);
    }
    if (e < r1) {
        int s = permSrc[e];
        accum8(a, *reinterpret_cast<const uint4*>(act + (size_t)s * D + f0));
    }

    #pragma unroll
    for (int j = 0; j < 8; j++) {
        if constexpr (GROUPS == 4) a[j] += __shfl_xor(a[j], 16);
        a[j] += __shfl_xor(a[j], 32);
    }

    if (g == 0) {
        float sc = nd[node];
        union { ushort u[8]; uint4 v; } H;
        #pragma unroll
        for (int j = 0; j < 8; j++) H.u[j] = f2bf(a[j] * sc);
        *reinterpret_cast<uint4*>(Rb + (size_t)node * D + f0) = H.v;
    }
}

// ================= MFMA GEMM, full-width tile (128 x CB*64 per block) =================
// Cb[n][Dout] = bf16( relu( A@B^T + bias ) * (post ? post[row] : 1) )
// One block per 128-row panel: A staged ONCE per K-step for all CB col-blocks.
// XCD co-location on row panels + global_load_lds + 16B-chunk XOR swizzle.

template<int CB>
__global__ __launch_bounds__(256) void gemm_full(
        const ushort* __restrict__ A, const ushort* __restrict__ B,
        const float* __restrict__ bias, const float* __restrict__ post,
        ushort* __restrict__ Cb, int n, int K, int nrowp) {
    constexpr int Dout = CB * 64;
    __shared__ __align__(16) ushort sA[128][64];
    __shared__ __align__(16) ushort sB[CB][64][64];
    const int tid = threadIdx.x;
    const int lane = tid & 63;
    const int wid = tid >> 6;
    const int l31 = lane & 31;
    const int kg = lane >> 5;         // k-group (0/1)

    // XCD co-location: consecutive row panels land on the same XCD in groups
    const int bid = blockIdx.x;
    const int rp = (bid >> 3) * 8 + (bid & 7);
    if (rp >= nrowp) return;
    const int row0 = rp * 128;

    // A staging: 1024 16B-chunks -> 4 per thread
    const ushort* gA[4];
    char* lA[4];
    #pragma unroll
    for (int i = 0; i < 4; i++) {
        int slot = i * 256 + wid * 64 + lane;
        int r = slot >> 3, ch = slot & 7;
        int gch = ch ^ (r & 7);
        int row = row0 + r; if (row >= n) row = n - 1;   // clamp: dup rows feed discarded C rows
        gA[i] = A + (size_t)row * K + gch * 8;
        lA[i] = (char*)&sA[0][0] + (size_t)(i * 256 + wid * 64) * 16;
    }
    // B staging: CB x 512 chunks -> CB x 2 per thread
    const ushort* gB[CB][2];
    char* lB[CB][2];
    #pragma unroll
    for (int cb = 0; cb < CB; cb++) {
        #pragma unroll
        for (int i = 0; i < 2; i++) {
            int slot = i * 256 + wid * 64 + lane;
            int r = slot >> 3, ch = slot & 7;
            int gch = ch ^ (r & 7);
            gB[cb][i] = B + (size_t)(cb * 64 + r) * K + gch * 8;
            lB[cb][i] = (char*)&sB[cb][0][0] + (size_t)(i * 256 + wid * 64) * 16;
        }
    }

    float16v acc[CB][2];
    #pragma unroll
    for (int cb = 0; cb < CB; cb++)
        #pragma unroll
        for (int h = 0; h < 2; h++)
            acc[cb][h] = (float16v){0.f,0.f,0.f,0.f,0.f,0.f,0.f,0.f,0.f,0.f,0.f,0.f,0.f,0.f,0.f,0.f};

    for (int k0 = 0; k0 < K; k0 += 64) {
        #pragma unroll
        for (int i = 0; i < 4; i++) gload16(gA[i] + k0, lA[i]);
        #pragma unroll
        for (int cb = 0; cb < CB; cb++)
            #pragma unroll
            for (int i = 0; i < 2; i++) gload16(gB[cb][i] + k0, lB[cb][i]);
        __syncthreads();

        #pragma unroll
        for (int ks = 0; ks < 4; ks++) {
            const int gw = ks * 2 + kg;
            const int rA = wid * 32 + l31;
            short8v a = *reinterpret_cast<const short8v*>(&sA[rA][(gw ^ (rA & 7)) * 8]);
            #pragma unroll
            for (int cb = 0; cb < CB; cb++) {
                short8v b0 = *reinterpret_cast<const short8v*>(&sB[cb][l31][(gw ^ (l31 & 7)) * 8]);
                short8v b1 = *reinterpret_cast<const short8v*>(&sB[cb][32 + l31][(gw ^ (l31 & 7)) * 8]);
                acc[cb][0] = __builtin_amdgcn_mfma_f32_32x32x16_bf16(a, b0, acc[cb][0], 0, 0, 0);
                acc[cb][1] = __builtin_amdgcn_mfma_f32_32x32x16_bf16(a, b1, acc[cb][1], 0, 0, 0);
            }
        }
        __syncthreads();
    }

    // epilogue: C/D layout: col = lane&31, row = (r&3) + 8*(r>>2) + 4*(lane>>5)
    const int rbase = row0 + wid * 32;
    #pragma unroll
    for (int cb = 0; cb < CB; cb++) {
        #pragma unroll
        for (int h = 0; h < 2; h++) {
            const int colg = cb * 64 + h * 32 + l31;
            const float bcol = bias[colg];
            #pragma unroll
            for (int r = 0; r < 16; r++) {
                int rowg = rbase + (r & 3) + 8 * (r >> 2) + 4 * kg;
                if (rowg < n) {
                    float v = fmaxf(acc[cb][h][r] + bcol, 0.0f);
                    if (post) v *= post[rowg];
                    Cb[(size_t)rowg * Dout + colg] = f2bf(v);
                }
            }
        }
    }
}

// ================= classifier: out = h @ Wc + bc  (h bf16, K=256, Dout=4) =================

__global__ __launch_bounds__(256) void classifier_kernel(
        const ushort* __restrict__ h, const float* __restrict__ Wc,
        const float* __restrict__ bc, float* __restrict__ out, int n) {
    __shared__ float Ws[256 * 4];
    int tid = threadIdx.x;
    for (int i = tid; i < 1024; i += 256) Ws[i] = Wc[i];
    __syncthreads();
    int node = blockIdx.x * 64 + (tid >> 2);
    int c = tid & 3;
    if (node < n) {
        float sum = bc[c];
        const ushort* hr = h + (size_t)node * 256;
        #pragma unroll
        for (int k0 = 0; k0 < 256; k0 += 8) {
            uint4 pk = *reinterpret_cast<const uint4*>(hr + k0);
            sum = fmaf(bf2f((ushort)(pk.x & 0xffff)), Ws[(k0 + 0) * 4 + c], sum);
            sum = fmaf(bf2f((ushort)(pk.x >> 16)),    Ws[(k0 + 1) * 4 + c], sum);
            sum = fmaf(bf2f((ushort)(pk.y & 0xffff)), Ws[(k0 + 2) * 4 + c], sum);
            sum = fmaf(bf2f((ushort)(pk.y >> 16)),    Ws[(k0 + 3) * 4 + c], sum);
            sum = fmaf(bf2f((ushort)(pk.z & 0xffff)), Ws[(k0 + 4) * 4 + c], sum);
            sum = fmaf(bf2f((ushort)(pk.z >> 16)),    Ws[(k0 + 5) * 4 + c], sum);
            sum = fmaf(bf2f((ushort)(pk.w & 0xffff)), Ws[(k0 + 6) * 4 + c], sum);
            sum = fmaf(bf2f((ushort)(pk.w >> 16)),    Ws[(k0 + 7) * 4 + c], sum);
        }
        out[(size_t)node * 4 + c] = sum;
    }
}

// ================= launch =================

extern "C" void kernel_launch(void* const* d_in, const int* in_sizes, int n_in,
                              void* d_out, int out_size, void* d_ws, size_t ws_size,
                              hipStream_t stream) {
    const float* x   = (const float*)d_in[0];
    const int*   src = (const int*)d_in[1];
    const int*   dst = (const int*)d_in[2];
    const float* W0 = (const float*)d_in[3];
    const float* b0 = (const float*)d_in[4];
    const float* W1 = (const float*)d_in[5];
    const float* b1 = (const float*)d_in[6];
    const float* W2 = (const float*)d_in[7];
    const float* b2 = (const float*)d_in[8];
    const float* W3 = (const float*)d_in[9];
    const float* b3 = (const float*)d_in[10];
    const float* Wc = (const float*)d_in[11];
    const float* bc = (const float*)d_in[12];
    const float* b[4] = {b0, b1, b2, b3};
    float* out = (float*)d_out;

    // ---- workspace layout ----
    ushort* actB = (ushort*)d_ws;                        // N*256 ushort
    ushort* Rb   = actB + (size_t)NN * 256;              // N*256 ushort
    float*  ns   = (float*)(Rb + (size_t)NN * 256);      // N f32
    float*  nd   = ns + NN;                              // N f32
    ushort* Wt   = (ushort*)(nd + NN);                   // 131072 ushort (all layers, transposed bf16)
    int2*   rowse   = (int2*)(Wt + 131072);              // N int2 (start,end)
    int*    permSrc = (int*)(rowse + NN);                // NBUCK*CAP int
    int*    dstCur  = permSrc + NBUCK * CAP;             // NBUCK
    int*    srcCur  = dstCur + NBUCK;                    // NBUCK
    // transient (setup only) aliased into Rb
    int2*   pairBuck = (int2*)Rb;                        // NBUCK*CAP int2 (8.0 MB)
    int*    srcBuck  = (int*)(pairBuck + NBUCK * CAP);   // NBUCK*CAP int  (4.0 MB)
    (void)in_sizes; (void)n_in; (void)out_size; (void)ws_size;

    // ---- bucketed CSR build ----
    initCur<<<1, 256, 0, stream>>>(dstCur, srcCur);
    partition_kernel<<<256, 256, 0, stream>>>(src, dst, dstCur, srcCur, pairBuck, srcBuck, NEDGE);
    convw_all<<<512, 256, 0, stream>>>(W0, W1, W2, W3, Wt);   // independent
    srcHistConv<<<NBUCK, 256, 0, stream>>>(srcBuck, srcCur, x, ns, actB, NN);
    dstBuild<<<NBUCK, 256, 0, stream>>>(pairBuck, dstCur, nd, rowse, permSrc, NN);

    const int dims[5] = {128, 128, 128, 256, 256};
    const int woff[4] = {0, 16384, 32768, 65536};
    const int nrowp = (NN + 127) / 128;
    const int nrowp8 = ((nrowp + 7) / 8) * 8;

    for (int l = 0; l < 4; l++) {
        int K = dims[l], Dout = dims[l + 1];   // agg runs at width K (input side)

        // Rb = bf16( nd * agg(actB) )
        int ablocks = (NN + 3) / 4;
        if (K == 128)
            agg_kernel<128><<<ablocks, 256, 0, stream>>>(actB, rowse, permSrc, nd, Rb, NN);
        else
            agg_kernel<256><<<ablocks, 256, 0, stream>>>(actB, rowse, permSrc, nd, Rb, NN);

        // actB' = bf16( relu(Rb@W + b) * (l<3 ? ns : 1) )
        const float* post = (l < 3) ? ns : nullptr;
        if (Dout == 128)
            gemm_full<2><<<nrowp8, 256, 0, stream>>>(Rb, Wt + woff[l], b[l], post, actB, NN, K, nrowp);
        else
            gemm_full<4><<<nrowp8, 256, 0, stream>>>(Rb, Wt + woff[l], b[l], post, actB, NN, K, nrowp);
    }

    classifier_kernel<<<(NN + 63) / 64, 256, 0, stream>>>(actB, Wc, bc, out, NN);
}

// Round 15
// 388.574 us; speedup vs baseline: 1.4678x; 1.4678x over previous
//
#include <hip/hip_runtime.h>
#include <cstdint>
#include <cstddef>

#define NN 100000
#define NEDGE 800000
#define NBUCK 196          // node buckets: id = node >> 9 (512 nodes per bucket)
#define RNG 512
#define CAP 5120           // fixed bucket capacity: mean 4096, sigma ~64 -> 16-sigma headroom

typedef __attribute__((ext_vector_type(8))) short short8v;
typedef __attribute__((ext_vector_type(16))) float float16v;

__device__ inline ushort f2bf(float f) {
    uint32_t u = __float_as_uint(f);
    u += 0x7fff + ((u >> 16) & 1);   // round-to-nearest-even
    return (ushort)(u >> 16);
}
__device__ inline float bf2f(ushort h) { return __uint_as_float(((uint32_t)h) << 16); }

__device__ inline void gload16(const void* g, void* lds) {
    __builtin_amdgcn_global_load_lds(
        (const __attribute__((address_space(1))) void*)g,
        (__attribute__((address_space(3))) void*)lds, 16, 0, 0);
}

// ================= bucketed CSR build (fixed-capacity buckets) =================

__global__ void initCur(int* __restrict__ dstCur, int* __restrict__ srcCur) {
    int i = threadIdx.x;
    if (i < NBUCK) { dstCur[i] = i * CAP; srcCur[i] = i * CAP; }
}

__global__ __launch_bounds__(256) void partition_kernel(
        const int* __restrict__ src, const int* __restrict__ dst,
        int* __restrict__ dstCur, int* __restrict__ srcCur,
        int2* __restrict__ pairBuck, int* __restrict__ srcBuck, int E) {
    __shared__ int cd[NBUCK], bd[NBUCK], cs[NBUCK], bs[NBUCK];
    const int CH = (E + gridDim.x - 1) / gridDim.x;
    const int lo = blockIdx.x * CH;
    const int hi = min(lo + CH, E);
    for (int i = threadIdx.x; i < NBUCK; i += 256) { cd[i] = 0; cs[i] = 0; }
    __syncthreads();
    for (int i = lo + threadIdx.x; i < hi; i += 256) {
        atomicAdd(&cd[dst[i] >> 9], 1);
        atomicAdd(&cs[src[i] >> 9], 1);
    }
    __syncthreads();
    for (int i = threadIdx.x; i < NBUCK; i += 256) {
        bd[i] = cd[i] ? atomicAdd(&dstCur[i], cd[i]) : 0;
        bs[i] = cs[i] ? atomicAdd(&srcCur[i], cs[i]) : 0;
        cd[i] = 0; cs[i] = 0;
    }
    __syncthreads();
    for (int i = lo + threadIdx.x; i < hi; i += 256) {
        int s = src[i], d = dst[i];
        int slot = atomicAdd(&cd[d >> 9], 1);
        pairBuck[bd[d >> 9] + slot] = make_int2(s, d);
        int slot2 = atomicAdd(&cs[s >> 9], 1);
        srcBuck[bs[s >> 9] + slot2] = s;
    }
}

// per-bucket src histogram -> ns; fused conversion of this bucket's x rows to bf16*ns
__global__ __launch_bounds__(256) void srcHistConv(
        const int* __restrict__ srcBuck, const int* __restrict__ srcCur,
        const float* __restrict__ x, float* __restrict__ ns,
        ushort* __restrict__ actB, int n) {
    __shared__ int h[RNG];
    __shared__ float sns[RNG];
    const int k = blockIdx.x;
    for (int i = threadIdx.x; i < RNG; i += 256) h[i] = 0;
    __syncthreads();
    const int lo = k * CAP, hi = srcCur[k];
    for (int i = lo + threadIdx.x; i < hi; i += 256)
        atomicAdd(&h[srcBuck[i] & (RNG - 1)], 1);
    __syncthreads();
    for (int i = threadIdx.x; i < RNG; i += 256) {
        float v = 1.0f / sqrtf((float)max(h[i], 1));
        sns[i] = v;
        int idx = k * RNG + i;
        if (idx < n) ns[idx] = v;
    }
    __syncthreads();
    const int base = k * RNG;
    for (int i = threadIdx.x; i < RNG * 32; i += 256) {
        int nl = i >> 5;
        int node = base + nl;
        if (node < n) {
            int f0 = (i & 31) * 4;
            float sc = sns[nl];
            float4 v = *reinterpret_cast<const float4*>(x + (size_t)node * 128 + f0);
            ushort4 hh;
            hh.x = f2bf(v.x * sc);
            hh.y = f2bf(v.y * sc);
            hh.z = f2bf(v.z * sc);
            hh.w = f2bf(v.w * sc);
            *reinterpret_cast<ushort4*>(actB + (size_t)node * 128 + f0) = hh;
        }
    }
}

// per-bucket dst histogram + scan -> rowse (start,end), nd; LDS-cursor scatter
__global__ __launch_bounds__(256) void dstBuild(const int2* __restrict__ pairBuck,
                                                const int* __restrict__ dstCur,
                                                float* __restrict__ nd, int2* __restrict__ rowse,
                                                int* __restrict__ permSrc, int n) {
    __shared__ int h[RNG];
    __shared__ int tsum[256];
    const int k = blockIdx.x;
    const int t = threadIdx.x;
    for (int i = t; i < RNG; i += 256) h[i] = 0;
    __syncthreads();
    const int lo = k * CAP, hi = dstCur[k];
    for (int i = lo + t; i < hi; i += 256)
        atomicAdd(&h[pairBuck[i].y & (RNG - 1)], 1);
    __syncthreads();
    int a0 = h[2 * t], a1 = h[2 * t + 1];
    tsum[t] = a0 + a1;
    __syncthreads();
    for (int off = 1; off < 256; off <<= 1) {
        int v = (t >= off) ? tsum[t - off] : 0;
        __syncthreads();
        tsum[t] += v;
        __syncthreads();
    }
    const int pre = lo + (t > 0 ? tsum[t - 1] : 0);
    const int r0 = pre, r1 = pre + a0;
    const int idx0 = k * RNG + 2 * t;
    if (idx0 < n)     { rowse[idx0]     = make_int2(r0, r1);      nd[idx0]     = 1.0f / sqrtf((float)max(a0, 1)); }
    if (idx0 + 1 < n) { rowse[idx0 + 1] = make_int2(r1, r1 + a1); nd[idx0 + 1] = 1.0f / sqrtf((float)max(a1, 1)); }
    h[2 * t] = r0;
    h[2 * t + 1] = r1;
    __syncthreads();
    for (int i = lo + t; i < hi; i += 256) {
        int2 p = pairBuck[i];
        int pos = atomicAdd(&h[p.y & (RNG - 1)], 1);
        permSrc[pos] = p.x;
    }
}

// ================= converters =================

__global__ void convw_all(const float* __restrict__ W0, const float* __restrict__ W1,
                          const float* __restrict__ W2, const float* __restrict__ W3,
                          ushort* __restrict__ Wt) {
    int idx = blockIdx.x * blockDim.x + threadIdx.x;
    if (idx >= 131072) return;
    const float* W; int K, logD, base;
    if (idx < 16384)      { W = W0; K = 128; logD = 7; base = 0; }
    else if (idx < 32768) { W = W1; K = 128; logD = 7; base = 16384; }
    else if (idx < 65536) { W = W2; K = 128; logD = 8; base = 32768; }
    else                  { W = W3; K = 256; logD = 8; base = 65536; }
    int loc = idx - base;
    int k = loc >> logD, d = loc & ((1 << logD) - 1);
    Wt[base + d * K + k] = f2bf(W[loc]);
}

// ================= CSR aggregation: 16B gather loads, edge-group MLP =================
// Rb[node] = bf16( nd[node] * sum_{e in CSR(node)} act[src[e]] )

__device__ inline void accum8(float* a, uint4 v) {
    a[0] += __uint_as_float(v.x << 16);
    a[1] += __uint_as_float(v.x & 0xffff0000u);
    a[2] += __uint_as_float(v.y << 16);
    a[3] += __uint_as_float(v.y & 0xffff0000u);
    a[4] += __uint_as_float(v.z << 16);
    a[5] += __uint_as_float(v.z & 0xffff0000u);
    a[6] += __uint_as_float(v.w << 16);
    a[7] += __uint_as_float(v.w & 0xffff0000u);
}

template<int D>
__global__ __launch_bounds__(256) void agg_kernel(
        const ushort* __restrict__ act, const int2* __restrict__ rowse,
        const int* __restrict__ permSrc, const float* __restrict__ nd,
        ushort* __restrict__ Rb, int n) {
    int node = blockIdx.x * 4 + (threadIdx.x >> 6);
    if (node >= n) return;
    int lane = threadIdx.x & 63;
    constexpr int GROUPS = (D == 256) ? 2 : 4;   // edge slices per wave
    constexpr int GL = 64 / GROUPS;              // lanes per slice (32 / 16)
    const int g  = lane / GL;
    const int gl = lane % GL;
    const int f0 = gl * 8;                       // 8 bf16 per lane (16B)
    float a[8] = {0.f,0.f,0.f,0.f,0.f,0.f,0.f,0.f};
    int2 se = rowse[node];
    int r0 = se.x, r1 = se.y;

    int e = r0 + g;
    for (; e + 3 * GROUPS < r1; e += 4 * GROUPS) {
        int s0 = permSrc[e];
        int s1 = permSrc[e + GROUPS];
        int s2 = permSrc[e + 2 * GROUPS];
        int s3 = permSrc[e + 3 * GROUPS];
        uint4 v0 = *reinterpret_cast<const uint4*>(act + (size_t)s0 * D + f0);
        uint4 v1 = *reinterpret_cast<const uint4*>(act + (size_t)s1 * D + f0);
        uint4 v2 = *reinterpret_cast<const uint4*>(act + (size_t)s2 * D + f0);
        uint4 v3 = *reinterpret_cast<const uint4*>(act + (size_t)s3 * D + f0);
        accum8(a, v0); accum8(a, v1); accum8(a, v2); accum8(a, v3);
    }
    // 2x unrolled middle: keeps 2 gathers in flight at low remaining degree
    for (; e + GROUPS < r1; e += 2 * GROUPS) {
        int s0 = permSrc[e];
        int s1 = permSrc[e + GROUPS];
        uint4 v0 = *reinterpret_cast<const uint4*>(act + (size_t)s0 * D + f0);
        uint4 v1 = *reinterpret_cast<const uint4*>(act + (size_t)s1 * D + f0);
        accum8(a, v0); accum8(a, v1);
    }
    if (e < r1) {
        int s = permSrc[e];
        accum8(a, *reinterpret_cast<const uint4*>(act + (size_t)s * D + f0));
    }

    #pragma unroll
    for (int j = 0; j < 8; j++) {
        if constexpr (GROUPS == 4) a[j] += __shfl_xor(a[j], 16);
        a[j] += __shfl_xor(a[j], 32);
    }

    if (g == 0) {
        float sc = nd[node];
        union { ushort u[8]; uint4 v; } H;
        #pragma unroll
        for (int j = 0; j < 8; j++) H.u[j] = f2bf(a[j] * sc);
        *reinterpret_cast<uint4*>(Rb + (size_t)node * D + f0) = H.v;
    }
}

// ================= MFMA GEMM with fused epilogue (R13 proven config) =================
// Cb[n][Dout] = bf16( relu( A@B^T + bias ) * (post ? post[row] : 1) )
// A, B plain bf16. 128x64 tile, 4 waves. XCD co-location + global_load_lds
// + 16B-chunk XOR swizzle (source- and read-side).

__global__ __launch_bounds__(256) void gemm_mfma(
        const ushort* __restrict__ A, const ushort* __restrict__ B,
        const float* __restrict__ bias, const float* __restrict__ post,
        ushort* __restrict__ Cb, int n, int K, int Dout, int logCB, int nrowp) {
    __shared__ __align__(16) ushort sA[128][64];
    __shared__ __align__(16) ushort sB[64][64];
    const int tid = threadIdx.x;
    const int lane = tid & 63;
    const int wid = tid >> 6;
    const int l31 = lane & 31;
    const int kg = lane >> 5;         // k-group (0/1)

    // XCD co-location decode
    const int bid = blockIdx.x;
    const int xcd = bid & 7;
    const int t = bid >> 3;
    const int cb2 = t & ((1 << logCB) - 1);
    const int rp = (t >> logCB) * 8 + xcd;
    if (rp >= nrowp) return;
    const int row0 = rp * 128;
    const int col0 = cb2 * 64;

    // per-issue global bases (k0-invariant) and wave-uniform LDS bases
    const ushort* gA[4];
    char* lA[4];
    #pragma unroll
    for (int i = 0; i < 4; i++) {
        int slot = i * 256 + wid * 64 + lane;
        int r = slot >> 3, ch = slot & 7;
        int gch = ch ^ (r & 7);
        int row = row0 + r; if (row >= n) row = n - 1;   // clamp: dup rows feed discarded C rows
        gA[i] = A + (size_t)row * K + gch * 8;
        lA[i] = (char*)&sA[0][0] + (size_t)(i * 256 + wid * 64) * 16;
    }
    const ushort* gB[2];
    char* lB[2];
    #pragma unroll
    for (int i = 0; i < 2; i++) {
        int slot = i * 256 + wid * 64 + lane;
        int r = slot >> 3, ch = slot & 7;
        int gch = ch ^ (r & 7);
        gB[i] = B + (size_t)(col0 + r) * K + gch * 8;
        lB[i] = (char*)&sB[0][0] + (size_t)(i * 256 + wid * 64) * 16;
    }

    float16v acc0 = {0.f,0.f,0.f,0.f,0.f,0.f,0.f,0.f,0.f,0.f,0.f,0.f,0.f,0.f,0.f,0.f};
    float16v acc1 = {0.f,0.f,0.f,0.f,0.f,0.f,0.f,0.f,0.f,0.f,0.f,0.f,0.f,0.f,0.f,0.f};

    for (int k0 = 0; k0 < K; k0 += 64) {
        #pragma unroll
        for (int i = 0; i < 4; i++) gload16(gA[i] + k0, lA[i]);
        #pragma unroll
        for (int i = 0; i < 2; i++) gload16(gB[i] + k0, lB[i]);
        __syncthreads();

        #pragma unroll
        for (int ks = 0; ks < 4; ks++) {
            const int gw = ks * 2 + kg;          // wanted global chunk
            const int rA = wid * 32 + l31;
            const int rB0 = l31, rB1 = 32 + l31;
            short8v a = *reinterpret_cast<const short8v*>(&sA[rA][(gw ^ (rA & 7)) * 8]);
            short8v b0 = *reinterpret_cast<const short8v*>(&sB[rB0][(gw ^ (rB0 & 7)) * 8]);
            short8v b1 = *reinterpret_cast<const short8v*>(&sB[rB1][(gw ^ (rB1 & 7)) * 8]);
            acc0 = __builtin_amdgcn_mfma_f32_32x32x16_bf16(a, b0, acc0, 0, 0, 0);
            acc1 = __builtin_amdgcn_mfma_f32_32x32x16_bf16(a, b1, acc1, 0, 0, 0);
        }
        __syncthreads();
    }

    // epilogue: C/D layout: col = lane&31, row = (r&3) + 8*(r>>2) + 4*(lane>>5)
    const int rbase = row0 + wid * 32;
    #pragma unroll
    for (int cb = 0; cb < 2; cb++) {
        const int colg = col0 + cb * 32 + l31;
        const float bcol = bias[colg];
        const float16v& acc = cb ? acc1 : acc0;
        #pragma unroll
        for (int r = 0; r < 16; r++) {
            int rowg = rbase + (r & 3) + 8 * (r >> 2) + 4 * kg;
            if (rowg < n) {
                float v = fmaxf(acc[r] + bcol, 0.0f);
                if (post) v *= post[rowg];
                Cb[(size_t)rowg * Dout + colg] = f2bf(v);
            }
        }
    }
}

// ================= classifier: out = h @ Wc + bc  (h bf16, K=256, Dout=4) =================

__global__ __launch_bounds__(256) void classifier_kernel(
        const ushort* __restrict__ h, const float* __restrict__ Wc,
        const float* __restrict__ bc, float* __restrict__ out, int n) {
    __shared__ float Ws[256 * 4];
    int tid = threadIdx.x;
    for (int i = tid; i < 1024; i += 256) Ws[i] = Wc[i];
    __syncthreads();
    int node = blockIdx.x * 64 + (tid >> 2);
    int c = tid & 3;
    if (node < n) {
        float sum = bc[c];
        const ushort* hr = h + (size_t)node * 256;
        #pragma unroll
        for (int k0 = 0; k0 < 256; k0 += 8) {
            uint4 pk = *reinterpret_cast<const uint4*>(hr + k0);
            sum = fmaf(bf2f((ushort)(pk.x & 0xffff)), Ws[(k0 + 0) * 4 + c], sum);
            sum = fmaf(bf2f((ushort)(pk.x >> 16)),    Ws[(k0 + 1) * 4 + c], sum);
            sum = fmaf(bf2f((ushort)(pk.y & 0xffff)), Ws[(k0 + 2) * 4 + c], sum);
            sum = fmaf(bf2f((ushort)(pk.y >> 16)),    Ws[(k0 + 3) * 4 + c], sum);
            sum = fmaf(bf2f((ushort)(pk.z & 0xffff)), Ws[(k0 + 4) * 4 + c], sum);
            sum = fmaf(bf2f((ushort)(pk.z >> 16)),    Ws[(k0 + 5) * 4 + c], sum);
            sum = fmaf(bf2f((ushort)(pk.w & 0xffff)), Ws[(k0 + 6) * 4 + c], sum);
            sum = fmaf(bf2f((ushort)(pk.w >> 16)),    Ws[(k0 + 7) * 4 + c], sum);
        }
        out[(size_t)node * 4 + c] = sum;
    }
}

// ================= launch =================

extern "C" void kernel_launch(void* const* d_in, const int* in_sizes, int n_in,
                              void* d_out, int out_size, void* d_ws, size_t ws_size,
                              hipStream_t stream) {
    const float* x   = (const float*)d_in[0];
    const int*   src = (const int*)d_in[1];
    const int*   dst = (const int*)d_in[2];
    const float* W0 = (const float*)d_in[3];
    const float* b0 = (const float*)d_in[4];
    const float* W1 = (const float*)d_in[5];
    const float* b1 = (const float*)d_in[6];
    const float* W2 = (const float*)d_in[7];
    const float* b2 = (const float*)d_in[8];
    const float* W3 = (const float*)d_in[9];
    const float* b3 = (const float*)d_in[10];
    const float* Wc = (const float*)d_in[11];
    const float* bc = (const float*)d_in[12];
    const float* b[4] = {b0, b1, b2, b3};
    float* out = (float*)d_out;

    // ---- workspace layout ----
    ushort* actB = (ushort*)d_ws;                        // N*256 ushort
    ushort* Rb   = actB + (size_t)NN * 256;              // N*256 ushort
    float*  ns   = (float*)(Rb + (size_t)NN * 256);      // N f32
    float*  nd   = ns + NN;                              // N f32
    ushort* Wt   = (ushort*)(nd + NN);                   // 131072 ushort (all layers, transposed bf16)
    int2*   rowse   = (int2*)(Wt + 131072);              // N int2 (start,end)
    int*    permSrc = (int*)(rowse + NN);                // NBUCK*CAP int
    int*    dstCur  = permSrc + NBUCK * CAP;             // NBUCK
    int*    srcCur  = dstCur + NBUCK;                    // NBUCK
    // transient (setup only) aliased into Rb
    int2*   pairBuck = (int2*)Rb;                        // NBUCK*CAP int2 (8.0 MB)
    int*    srcBuck  = (int*)(pairBuck + NBUCK * CAP);   // NBUCK*CAP int  (4.0 MB)
    (void)in_sizes; (void)n_in; (void)out_size; (void)ws_size;

    // ---- bucketed CSR build ----
    initCur<<<1, 256, 0, stream>>>(dstCur, srcCur);
    partition_kernel<<<256, 256, 0, stream>>>(src, dst, dstCur, srcCur, pairBuck, srcBuck, NEDGE);
    convw_all<<<512, 256, 0, stream>>>(W0, W1, W2, W3, Wt);   // independent
    srcHistConv<<<NBUCK, 256, 0, stream>>>(srcBuck, srcCur, x, ns, actB, NN);
    dstBuild<<<NBUCK, 256, 0, stream>>>(pairBuck, dstCur, nd, rowse, permSrc, NN);

    const int dims[5] = {128, 128, 128, 256, 256};
    const int woff[4] = {0, 16384, 32768, 65536};
    const int nrowp = (NN + 127) / 128;
    const int nrowp8 = ((nrowp + 7) / 8) * 8;

    for (int l = 0; l < 4; l++) {
        int K = dims[l], Dout = dims[l + 1];   // agg runs at width K (input side)
        int logCB = (Dout == 128) ? 1 : 2;
        int CB = Dout / 64;

        // Rb = bf16( nd * agg(actB) )
        int ablocks = (NN + 3) / 4;
        if (K == 128)
            agg_kernel<128><<<ablocks, 256, 0, stream>>>(actB, rowse, permSrc, nd, Rb, NN);
        else
            agg_kernel<256><<<ablocks, 256, 0, stream>>>(actB, rowse, permSrc, nd, Rb, NN);

        // actB' = bf16( relu(Rb@W + b) * (l<3 ? ns : 1) )
        const float* post = (l < 3) ? ns : nullptr;
        gemm_mfma<<<nrowp8 * CB, 256, 0, stream>>>(Rb, Wt + woff[l], b[l], post,
                                                   actB, NN, K, Dout, logCB, nrowp);
    }

    classifier_kernel<<<(NN + 63) / 64, 256, 0, stream>>>(actB, Wc, bc, out, NN);
}